// Round 7
// baseline (1243.217 us; speedup 1.0000x reference)
//
#include <hip/hip_runtime.h>

#define BN 512            // matrix dimension n
#define NW 16             // waves per block (1024 threads)
#define RPW 32            // rows per wave
#define SPW 16            // steps per pass (2 rows in flight per step)

static constexpr float kScale = 28.853900817779268f;   // log2(e)/tau

__device__ __forceinline__ float fexp2(float x){ return __builtin_amdgcn_exp2f(x); }
__device__ __forceinline__ float flog2(float x){ return __builtin_amdgcn_logf(x); }
__device__ __forceinline__ float frcp (float x){ return __builtin_amdgcn_rcpf(x); }

// round-to-nearest-even f32->bf16, pack two into u32 (a=lo16, b=hi16)
__device__ __forceinline__ unsigned rtne_pack(float a, float b){
    unsigned ua = __float_as_uint(a), ub = __float_as_uint(b);
    unsigned lo = (ua + 0x7fffu + ((ua >> 16) & 1u)) >> 16;
    unsigned hi = (ub + 0x7fffu + ((ub >> 16) & 1u)) & 0xffff0000u;
    return lo | hi;
}
__device__ __forceinline__ void unpack2(unsigned w, float& lo, float& hi){
    lo = __uint_as_float(w << 16);
    hi = __uint_as_float(w & 0xffff0000u);
}

// padded (stride-9, coprime with 32 banks) cred slot for position p in [0,512)
__device__ __forceinline__ int credIdx(int p){
    return ((p >> 8) * 288) + (((p & 255) >> 3) * 9) + (p & 7);
}

// waves_per_eu(4,4): EXACTLY 4 waves/EU -> hard 128-VGPR budget. Without it the
// backend's occupancy heuristic targets 8 waves/EU (64 VGPR) for 16-wave blocks
// and SPILLS the pipeline to scratch (R4-R6: 1.8 GB scratch writes, 4x slower).
// Grid == 256 == #CUs, so >16 waves/CU occupancy is unreachable anyway.
__global__ __launch_bounds__(1024)
__attribute__((amdgpu_waves_per_eu(4, 4)))
void sinkhorn_fused(
    const float* __restrict__ logits, float* __restrict__ out,
    unsigned short* __restrict__ ws, int use_ws)
{
    __shared__ float Bf[BN];          // linear col factor (position-indexed)
    __shared__ float SL[BN];          // latest row sums (pass 9's survive)
    __shared__ float cred[NW][576];   // padded per-wave col partials (36,864 B)

    const int b = blockIdx.x;
    const size_t base = (size_t)b * BN * BN;
    const float* __restrict__ Zb = logits + base;
    float* __restrict__ Ob = out + base;
    unsigned short* __restrict__ Mb = use_ws ? (ws + base) : (unsigned short*)Ob;

    const int tid  = threadIdx.x;
    const int lane = tid & 63;
    const int wave = tid >> 6;
    const int g    = lane >> 5;       // row subgroup (2 rows in flight)
    const int gl   = lane & 31;

    // per-lane M pointers: step s -> row wave*32 + 2s + g
    const unsigned short* Mr0 = Mb + (size_t)(wave * RPW + g) * BN + gl * 8;
    const unsigned short* Mr1 = Mr0 + 256;

#define LDA(s) (*reinterpret_cast<const int4*>(Mr0 + (size_t)(s) * (2 * BN)))
#define LDB(s) (*reinterpret_cast<const int4*>(Mr1 + (size_t)(s) * (2 * BN)))

#define STEP(sidx, W0, W1)                                                         \
    {                                                                              \
        float e0[8], e1[8];                                                        \
        unpack2((unsigned)(W0).x, e0[0], e0[1]); unpack2((unsigned)(W0).y, e0[2], e0[3]); \
        unpack2((unsigned)(W0).z, e0[4], e0[5]); unpack2((unsigned)(W0).w, e0[6], e0[7]); \
        unpack2((unsigned)(W1).x, e1[0], e1[1]); unpack2((unsigned)(W1).y, e1[2], e1[3]); \
        unpack2((unsigned)(W1).z, e1[4], e1[5]); unpack2((unsigned)(W1).w, e1[6], e1[7]); \
        float a0 = 0.f, a1 = 0.f, a2 = 0.f, a3 = 0.f;                              \
        _Pragma("unroll")                                                          \
        for (int k = 0; k < 4; ++k) {                                              \
            a0 = fmaf(e0[k],     bl0[k],     a0);                                  \
            a1 = fmaf(e0[4 + k], bl0[4 + k], a1);                                  \
            a2 = fmaf(e1[k],     bl1[k],     a2);                                  \
            a3 = fmaf(e1[4 + k], bl1[4 + k], a3);                                  \
        }                                                                          \
        float s = (a0 + a1) + (a2 + a3);                                           \
        _Pragma("unroll")                                                          \
        for (int d = 16; d > 0; d >>= 1) s += __shfl_xor(s, d, 64);                \
        const float A = frcp(s);                                                   \
        if (gl == 0) SL[wave * RPW + 2 * (sidx) + g] = s;                          \
        _Pragma("unroll")                                                          \
        for (int k = 0; k < 8; ++k) {                                              \
            ca0[k] = fmaf(e0[k], A, ca0[k]);                                       \
            ca1[k] = fmaf(e1[k], A, ca1[k]);                                       \
        }                                                                          \
    }

    // ---------------- pass 0: fp32 read, exact row LSE, M = bf16(2^(t-m-lg2s+64)) ----------------
    {
        float ca[8] = {0.f,0.f,0.f,0.f,0.f,0.f,0.f,0.f};

        #pragma unroll 2
        for (int r = 0; r < RPW; ++r) {
            const int i = wave * RPW + r;
            const float4 x0 = *reinterpret_cast<const float4*>(Zb + (size_t)i * BN + 4 * lane);
            const float4 x1 = *reinterpret_cast<const float4*>(Zb + (size_t)i * BN + 256 + 4 * lane);

            float t[8];
            t[0] = x0.x * kScale; t[1] = x0.y * kScale; t[2] = x0.z * kScale; t[3] = x0.w * kScale;
            t[4] = x1.x * kScale; t[5] = x1.y * kScale; t[6] = x1.z * kScale; t[7] = x1.w * kScale;

            float m = t[0];
            #pragma unroll
            for (int k = 1; k < 8; ++k) m = fmaxf(m, t[k]);
            #pragma unroll
            for (int d = 32; d > 0; d >>= 1) m = fmaxf(m, __shfl_xor(m, d, 64));

            float p[8], s = 0.f;
            #pragma unroll
            for (int k = 0; k < 8; ++k) { p[k] = fexp2(t[k] - m); s += p[k]; }
            #pragma unroll
            for (int d = 32; d > 0; d >>= 1) s += __shfl_xor(s, d, 64);

            const float f = fexp2(64.0f - flog2(s));   // 2^64 / s
            float Mv[8];
            #pragma unroll
            for (int k = 0; k < 8; ++k) { Mv[k] = p[k] * f; ca[k] += Mv[k]; }

            int4 packed;
            packed.x = (int)rtne_pack(Mv[0], Mv[1]);
            packed.y = (int)rtne_pack(Mv[2], Mv[3]);
            packed.z = (int)rtne_pack(Mv[4], Mv[5]);
            packed.w = (int)rtne_pack(Mv[6], Mv[7]);
            *reinterpret_cast<int4*>(Mb + (size_t)i * BN + lane * 8) = packed;
        }

        const int cbase = (lane < 32) ? lane * 9 : 288 + (lane - 32) * 9;
        #pragma unroll
        for (int k = 0; k < 8; ++k) cred[wave][cbase + k] = ca[k];
        __syncthreads();                 // drains M writes; M now visible
    }

    // prefetch pass-1 steps 0,1 (named regs, live across the barrier)
    int4 A0 = LDA(0), A1 = LDB(0);
    int4 B0 = LDA(1), B1 = LDB(1);

    if (tid < BN) {
        const int ci = credIdx(tid);
        float s = 0.f;
        #pragma unroll
        for (int wv = 0; wv < NW; ++wv) s += cred[wv][ci];
        Bf[tid] = frcp(s);
    }
    __syncthreads();

    // ---------------- passes 1..9: linear Sinkhorn, depth-2 named-var pipeline ----------------
    for (int it = 1; it < 10; ++it) {
        float bl0[8], bl1[8];
        #pragma unroll
        for (int k = 0; k < 8; ++k) { bl0[k] = Bf[gl * 8 + k]; bl1[k] = Bf[256 + gl * 8 + k]; }
        float ca0[8] = {0.f,0.f,0.f,0.f,0.f,0.f,0.f,0.f};
        float ca1[8] = {0.f,0.f,0.f,0.f,0.f,0.f,0.f,0.f};

        #pragma unroll
        for (int s2 = 0; s2 < SPW; s2 += 2) {
            STEP(s2, A0, A1);
            A0 = LDA((s2 + 2) & 15); A1 = LDB((s2 + 2) & 15);   // &15 wraps tail -> next-pass prefetch
            STEP(s2 + 1, B0, B1);
            B0 = LDA((s2 + 3) & 15); B1 = LDB((s2 + 3) & 15);
        }

        #pragma unroll
        for (int k = 0; k < 8; ++k) {
            ca0[k] += __shfl_xor(ca0[k], 32, 64);
            ca1[k] += __shfl_xor(ca1[k], 32, 64);
        }
        if (lane < 32) {
            #pragma unroll
            for (int k = 0; k < 8; ++k) {
                cred[wave][gl * 9 + k]       = ca0[k];
                cred[wave][288 + gl * 9 + k] = ca1[k];
            }
        }
        __syncthreads();
        if (tid < BN) {
            const int ci = credIdx(tid);
            float s = 0.f;
            #pragma unroll
            for (int wv = 0; wv < NW; ++wv) s += cred[wv][ci];
            Bf[tid] = frcp(s);
        }
        __syncthreads();
    }

    // ---------------- final: out = M * A_i * B_j ----------------
    {
        float bf[8];
        #pragma unroll
        for (int k = 0; k < 8; ++k) bf[k] = Bf[8 * lane + k];

        auto emit_row = [&](int j) {
            const int4 w = *reinterpret_cast<const int4*>(Mb + (size_t)j * BN + lane * 8);
            float e[8];
            unpack2((unsigned)w.x, e[0], e[1]); unpack2((unsigned)w.y, e[2], e[3]);
            unpack2((unsigned)w.z, e[4], e[5]); unpack2((unsigned)w.w, e[6], e[7]);
            const float A = frcp(SL[j]);
            float4 o0, o1;
            o0.x = e[0] * A * bf[0]; o0.y = e[1] * A * bf[1];
            o0.z = e[2] * A * bf[2]; o0.w = e[3] * A * bf[3];
            o1.x = e[4] * A * bf[4]; o1.y = e[5] * A * bf[5];
            o1.z = e[6] * A * bf[6]; o1.w = e[7] * A * bf[7];
            *reinterpret_cast<float4*>(Ob + (size_t)j * BN + 4 * lane) = o0;
            *reinterpret_cast<float4*>(Ob + (size_t)j * BN + 256 + 4 * lane) = o1;
        };

        if (use_ws) {
            // M in scratch: no aliasing; wave-owned rows
            #pragma unroll 2
            for (int r = 0; r < RPW; ++r) emit_row(wave * RPW + r);
        } else {
            // M aliases out: descending power-of-2 ranges; fp32 write of row j clobbers
            // M rows 2j,2j+1, always in an already-consumed (higher) range.
            for (int L = 256; L >= 1; L >>= 1) {
                for (int j = L + wave; j < 2 * L; j += NW) emit_row(j);
                __syncthreads();
            }
            if (wave == 0) emit_row(0);
        }
    }
#undef LDA
#undef LDB
#undef STEP
}

extern "C" void kernel_launch(void* const* d_in, const int* in_sizes, int n_in,
                              void* d_out, int out_size, void* d_ws, size_t ws_size,
                              hipStream_t stream) {
    const float* logits = (const float*)d_in[0];
    float* out = (float*)d_out;
    const int B = in_sizes[0] / (BN * BN);   // 256
    const size_t need = (size_t)B * BN * BN * sizeof(unsigned short);  // 128 MB
    const int use_ws = (ws_size >= need) ? 1 : 0;
    hipLaunchKernelGGL(sinkhorn_fused, dim3(B), dim3(1024), 0, stream,
                       logits, out, (unsigned short*)d_ws, use_ws);
}

// Round 8
// 328.974 us; speedup vs baseline: 3.7791x; 3.7791x over previous
//
#include <hip/hip_runtime.h>

#define BN 512            // matrix dimension n
#define NW 16             // waves per block (1024 threads)
#define RPW 32            // rows per wave

static constexpr float kScale = 28.853900817779268f;   // log2(e)/tau

__device__ __forceinline__ float fexp2(float x){ return __builtin_amdgcn_exp2f(x); }
__device__ __forceinline__ float flog2(float x){ return __builtin_amdgcn_logf(x); }
__device__ __forceinline__ float frcp (float x){ return __builtin_amdgcn_rcpf(x); }

// round-to-nearest-even f32->bf16, pack two into u32 (a=lo16, b=hi16)
__device__ __forceinline__ unsigned rtne_pack(float a, float b){
    unsigned ua = __float_as_uint(a), ub = __float_as_uint(b);
    unsigned lo = (ua + 0x7fffu + ((ua >> 16) & 1u)) >> 16;
    unsigned hi = (ub + 0x7fffu + ((ub >> 16) & 1u)) & 0xffff0000u;
    return lo | hi;
}
__device__ __forceinline__ void unpack2(unsigned w, float& lo, float& hi){
    lo = __uint_as_float(w << 16);
    hi = __uint_as_float(w & 0xffff0000u);
}

// padded (stride-9, coprime with 32 banks) cred slot for position p in [0,512)
__device__ __forceinline__ int credIdx(int p){
    return ((p >> 8) * 288) + (((p & 255) >> 3) * 9) + (p & 7);
}

// (1024,1): the ONLY empirically non-spilling config (R2/R3). The allocator
// pins 16-wave blocks at 64 VGPRs regardless of launch_bounds/waves_per_eu
// (R4-R7: 1.8 GB scratch, 4x slower) -> the kernel must FIT ~64 VGPRs.
__global__ __launch_bounds__(1024, 1) void sinkhorn_fused(
    const float* __restrict__ logits, float* __restrict__ out,
    unsigned short* __restrict__ ws, int use_ws)
{
    __shared__ float Bf[BN];          // linear col factor (position-indexed)
    __shared__ float SL[BN];          // latest row sums (pass 9's survive)
    __shared__ float cred[NW][576];   // padded per-wave col partials (36,864 B)

    const int b = blockIdx.x;
    const size_t base = (size_t)b * BN * BN;
    const float* __restrict__ Zb = logits + base;
    float* __restrict__ Ob = out + base;
    unsigned short* __restrict__ Mb = use_ws ? (ws + base) : (unsigned short*)Ob;

    const int tid  = threadIdx.x;
    const int lane = tid & 63;
    const int wave = tid >> 6;

    // ---------------- pass 0: fp32 read, exact row LSE, M = bf16(2^(t-m-lg2s+64)) ----------------
    // (R3-identical)
    {
        float ca[8] = {0.f,0.f,0.f,0.f,0.f,0.f,0.f,0.f};

        #pragma unroll 2
        for (int r = 0; r < RPW; ++r) {
            const int i = wave * RPW + r;
            const float4 x0 = *reinterpret_cast<const float4*>(Zb + (size_t)i * BN + 4 * lane);
            const float4 x1 = *reinterpret_cast<const float4*>(Zb + (size_t)i * BN + 256 + 4 * lane);

            float t[8];
            t[0] = x0.x * kScale; t[1] = x0.y * kScale; t[2] = x0.z * kScale; t[3] = x0.w * kScale;
            t[4] = x1.x * kScale; t[5] = x1.y * kScale; t[6] = x1.z * kScale; t[7] = x1.w * kScale;

            float m = t[0];
            #pragma unroll
            for (int k = 1; k < 8; ++k) m = fmaxf(m, t[k]);
            #pragma unroll
            for (int d = 32; d > 0; d >>= 1) m = fmaxf(m, __shfl_xor(m, d, 64));

            float p[8], s = 0.f;
            #pragma unroll
            for (int k = 0; k < 8; ++k) { p[k] = fexp2(t[k] - m); s += p[k]; }
            #pragma unroll
            for (int d = 32; d > 0; d >>= 1) s += __shfl_xor(s, d, 64);

            const float f = fexp2(64.0f - flog2(s));   // 2^64 / s
            float Mv[8];
            #pragma unroll
            for (int k = 0; k < 8; ++k) { Mv[k] = p[k] * f; ca[k] += Mv[k]; }

            int4 packed;
            packed.x = (int)rtne_pack(Mv[0], Mv[1]);
            packed.y = (int)rtne_pack(Mv[2], Mv[3]);
            packed.z = (int)rtne_pack(Mv[4], Mv[5]);
            packed.w = (int)rtne_pack(Mv[6], Mv[7]);
            *reinterpret_cast<int4*>(Mb + (size_t)i * BN + lane * 8) = packed;
        }

        const int cbase = (lane < 32) ? lane * 9 : 288 + (lane - 32) * 9;
        #pragma unroll
        for (int k = 0; k < 8; ++k) cred[wave][cbase + k] = ca[k];
        __syncthreads();                 // drains M writes; M now visible
    }

    // per-wave M base: row wave*32 + r, lane's 8 positions at byte offset 16*lane
    const unsigned short* Mw = Mb + (size_t)(wave * RPW) * BN + lane * 8;
#define LD(r) (*reinterpret_cast<const int4*>(Mw + (size_t)(r) * BN))

    // prefetch pass-1 rows 0..3 (named regs, live across the barrier)
    int4 W0 = LD(0), W1 = LD(1), W2 = LD(2), W3 = LD(3);

    if (tid < BN) {
        const int ci = credIdx(tid);
        float s = 0.f;
        #pragma unroll
        for (int wv = 0; wv < NW; ++wv) s += cred[wv][ci];
        Bf[tid] = frcp(s);
    }
    __syncthreads();

#define STEP1(ridx, W)                                                             \
    {                                                                              \
        float e[8];                                                                \
        unpack2((unsigned)(W).x, e[0], e[1]); unpack2((unsigned)(W).y, e[2], e[3]); \
        unpack2((unsigned)(W).z, e[4], e[5]); unpack2((unsigned)(W).w, e[6], e[7]); \
        float a0 = 0.f, a1 = 0.f, a2 = 0.f, a3 = 0.f;                              \
        a0 = fmaf(e[0], bl[0], a0); a1 = fmaf(e[1], bl[1], a1);                    \
        a2 = fmaf(e[2], bl[2], a2); a3 = fmaf(e[3], bl[3], a3);                    \
        a0 = fmaf(e[4], bl[4], a0); a1 = fmaf(e[5], bl[5], a1);                    \
        a2 = fmaf(e[6], bl[6], a2); a3 = fmaf(e[7], bl[7], a3);                    \
        float s = (a0 + a1) + (a2 + a3);                                           \
        _Pragma("unroll")                                                          \
        for (int d = 32; d > 0; d >>= 1) s += __shfl_xor(s, d, 64);                \
        const float A = frcp(s);                                                   \
        if (lane == 0) SL[wave * RPW + (ridx)] = s;                                \
        _Pragma("unroll")                                                          \
        for (int k = 0; k < 8; ++k) ca[k] = fmaf(e[k], A, ca[k]);                  \
    }

    // ---------------- passes 1..9: 1 row/step, depth-4 named rotation ----------------
    for (int it = 1; it < 10; ++it) {
        float bl[8];
        #pragma unroll
        for (int k = 0; k < 8; ++k) bl[k] = Bf[8 * lane + k];
        float ca[8] = {0.f,0.f,0.f,0.f,0.f,0.f,0.f,0.f};

        #pragma unroll 1
        for (int r = 0; r < RPW; r += 4) {
            STEP1(r + 0, W0); W0 = LD((r + 4) & 31);   // &31: tail wraps -> next-pass prefetch
            STEP1(r + 1, W1); W1 = LD((r + 5) & 31);
            STEP1(r + 2, W2); W2 = LD((r + 6) & 31);
            STEP1(r + 3, W3); W3 = LD((r + 7) & 31);
        }

        const int cbase = (lane < 32) ? lane * 9 : 288 + (lane - 32) * 9;
        #pragma unroll
        for (int k = 0; k < 8; ++k) cred[wave][cbase + k] = ca[k];
        __syncthreads();
        if (tid < BN) {
            const int ci = credIdx(tid);
            float s = 0.f;
            #pragma unroll
            for (int wv = 0; wv < NW; ++wv) s += cred[wv][ci];
            Bf[tid] = frcp(s);
        }
        __syncthreads();
    }

    // ---------------- final: out = M * A_i * B_j (R3-identical) ----------------
    {
        float bf[8];
        #pragma unroll
        for (int k = 0; k < 8; ++k) bf[k] = Bf[8 * lane + k];

        auto emit_row = [&](int j) {
            const int4 w = *reinterpret_cast<const int4*>(Mb + (size_t)j * BN + lane * 8);
            float e[8];
            unpack2((unsigned)w.x, e[0], e[1]); unpack2((unsigned)w.y, e[2], e[3]);
            unpack2((unsigned)w.z, e[4], e[5]); unpack2((unsigned)w.w, e[6], e[7]);
            const float A = frcp(SL[j]);
            float4 o0, o1;
            o0.x = e[0] * A * bf[0]; o0.y = e[1] * A * bf[1];
            o0.z = e[2] * A * bf[2]; o0.w = e[3] * A * bf[3];
            o1.x = e[4] * A * bf[4]; o1.y = e[5] * A * bf[5];
            o1.z = e[6] * A * bf[6]; o1.w = e[7] * A * bf[7];
            *reinterpret_cast<float4*>(Ob + (size_t)j * BN + 4 * lane) = o0;
            *reinterpret_cast<float4*>(Ob + (size_t)j * BN + 256 + 4 * lane) = o1;
        };

        if (use_ws) {
            #pragma unroll 2
            for (int r = 0; r < RPW; ++r) emit_row(wave * RPW + r);
        } else {
            // M aliases out: descending power-of-2 ranges; fp32 write of row j clobbers
            // M rows 2j,2j+1, always in an already-consumed (higher) range.
            for (int L = 256; L >= 1; L >>= 1) {
                for (int j = L + wave; j < 2 * L; j += NW) emit_row(j);
                __syncthreads();
            }
            if (wave == 0) emit_row(0);
        }
    }
#undef LD
#undef STEP1
}

extern "C" void kernel_launch(void* const* d_in, const int* in_sizes, int n_in,
                              void* d_out, int out_size, void* d_ws, size_t ws_size,
                              hipStream_t stream) {
    const float* logits = (const float*)d_in[0];
    float* out = (float*)d_out;
    const int B = in_sizes[0] / (BN * BN);   // 256
    const size_t need = (size_t)B * BN * BN * sizeof(unsigned short);  // 128 MB
    const int use_ws = (ws_size >= need) ? 1 : 0;
    hipLaunchKernelGGL(sinkhorn_fused, dim3(B), dim3(1024), 0, stream,
                       logits, out, (unsigned short*)d_ws, use_ws);
}